// Round 4
// baseline (472.716 us; speedup 1.0000x reference)
//
#include <hip/hip_runtime.h>
#include <hip/hip_bf16.h>

// B=8, S=2048, H=512. out[b,i,:] = sum_{j<i} exp(q_i.x_j) x_j / (sum_{j<i} exp(q_i.x_j) + 1e-10)
// q = X @ W^T + b.
// R4: LDS-pipe-bound diagnosis -> all MFMA operands loaded directly from global (L2-resident),
// one independent wave per 16 query rows, no barriers, no atomics, no staging.
#define BATCH 8
#define SEQ   2048
#define DIM   512

typedef __bf16 bf16x8 __attribute__((ext_vector_type(8)));
typedef float  f32x4  __attribute__((ext_vector_type(4)));

__device__ __forceinline__ ushort f2bf(float f) {
    union { float f; unsigned u; } c; c.f = f;
    unsigned u = c.u;
    u += 0x7fffu + ((u >> 16) & 1u);   // round-to-nearest-even
    return (ushort)(u >> 16);
}

// ---------------- prep: X f32 -> Xb bf16 (row-major) + Xt bf16 (transposed [b][h][s]) ---------
__global__ __launch_bounds__(256) void prep_kernel(const float* __restrict__ X,
                                                   ushort* __restrict__ Xb,
                                                   ushort* __restrict__ Xt) {
    __shared__ ushort T[32 * 33];
    int t   = threadIdx.x;
    int bid = blockIdx.x;              // 8 * 64 * 16 = 8192
    int b   = bid >> 10;
    int st  = (bid >> 4) & 63;
    int ht  = bid & 15;
    int s0 = st * 32, h0 = ht * 32;

    int r  = t >> 3;                   // 0..31 (s within tile)
    int c4 = (t & 7) * 4;              // 0..28 (h within tile)
    size_t src = ((size_t)(b * SEQ + s0 + r)) * DIM + h0 + c4;
    float4 v = *(const float4*)(X + src);
    ushort u0 = f2bf(v.x), u1 = f2bf(v.y), u2 = f2bf(v.z), u3 = f2bf(v.w);
    ushort4 uv; uv.x = u0; uv.y = u1; uv.z = u2; uv.w = u3;
    *(ushort4*)(Xb + src) = uv;
    T[(c4 + 0) * 33 + r] = u0;
    T[(c4 + 1) * 33 + r] = u1;
    T[(c4 + 2) * 33 + r] = u2;
    T[(c4 + 3) * 33 + r] = u3;
    __syncthreads();
    int hh = t >> 3;                   // 0..31 (h)
    int sc = (t & 7) * 4;              // 0..28 (s)
    ushort4 w;
    w.x = T[hh * 33 + sc + 0];
    w.y = T[hh * 33 + sc + 1];
    w.z = T[hh * 33 + sc + 2];
    w.w = T[hh * 33 + sc + 3];
    *(ushort4*)(Xt + ((size_t)(b * DIM + h0 + hh)) * SEQ + s0 + sc) = w;
}

// ---------------- wconv: W f32 -> bf16 ----------------
__global__ __launch_bounds__(256) void wconv_kernel(const float* __restrict__ W,
                                                    ushort* __restrict__ Wb) {
    int gt = blockIdx.x * 256 + threadIdx.x;   // 128 blocks, 8 elems each
    size_t base = (size_t)gt * 8;
    float4 a = *(const float4*)(W + base);
    float4 c = *(const float4*)(W + base + 4);
    ushort4 lo, hi;
    lo.x = f2bf(a.x); lo.y = f2bf(a.y); lo.z = f2bf(a.z); lo.w = f2bf(a.w);
    hi.x = f2bf(c.x); hi.y = f2bf(c.y); hi.z = f2bf(c.z); hi.w = f2bf(c.w);
    *(ushort4*)(Wb + base)     = lo;
    *(ushort4*)(Wb + base + 4) = hi;
}

// ---------------- qgemm: Qb = bf16(Xb @ Wb^T + bias) ----------------
// M=B*S=16384, N=512, K=512. 128x128 tile, 4 waves (each 64x64), K-step 32.
__global__ __launch_bounds__(256, 2) void qgemm_kernel(const ushort* __restrict__ Xb,
                                                       const ushort* __restrict__ Wb,
                                                       const float* __restrict__ bias,
                                                       ushort* __restrict__ Qb) {
    __shared__ ushort At[128 * 40];
    __shared__ ushort Bt[128 * 40];
    int t   = threadIdx.x;
    int bid = blockIdx.x;              // 128 mtiles * 4 ntiles
    int mt = bid >> 2, nt = bid & 3;
    int m0 = mt << 7, n0 = nt << 7;
    int w  = t >> 6, l = t & 63, ln = l & 15, lg = l >> 4;
    int wr = w >> 1, wc = w & 1;

    f32x4 acc[4][4] = {};
    int srow = t >> 2;                 // 0..63
    int sc8  = (t & 3) * 8;            // 0,8,16,24

    for (int ks = 0; ks < 16; ++ks) {
        uint4 va0 = *(const uint4*)(Xb + (size_t)(m0 + srow) * 512 + ks * 32 + sc8);
        uint4 va1 = *(const uint4*)(Xb + (size_t)(m0 + 64 + srow) * 512 + ks * 32 + sc8);
        uint4 vb0 = *(const uint4*)(Wb + (size_t)(n0 + srow) * 512 + ks * 32 + sc8);
        uint4 vb1 = *(const uint4*)(Wb + (size_t)(n0 + 64 + srow) * 512 + ks * 32 + sc8);
        __syncthreads();               // previous iter done reading LDS
        *(uint4*)&At[srow * 40 + sc8]        = va0;
        *(uint4*)&At[(64 + srow) * 40 + sc8] = va1;
        *(uint4*)&Bt[srow * 40 + sc8]        = vb0;
        *(uint4*)&Bt[(64 + srow) * 40 + sc8] = vb1;
        __syncthreads();
        bf16x8 af[4], bfr[4];
#pragma unroll
        for (int r = 0; r < 4; ++r)
            af[r] = *(const bf16x8*)&At[(wr * 64 + r * 16 + ln) * 40 + lg * 8];
#pragma unroll
        for (int c = 0; c < 4; ++c)
            bfr[c] = *(const bf16x8*)&Bt[(wc * 64 + c * 16 + ln) * 40 + lg * 8];
#pragma unroll
        for (int r = 0; r < 4; ++r)
#pragma unroll
            for (int c = 0; c < 4; ++c)
                acc[r][c] = __builtin_amdgcn_mfma_f32_16x16x32_bf16(af[r], bfr[c], acc[r][c], 0, 0, 0);
    }

    float bv[4];
#pragma unroll
    for (int c = 0; c < 4; ++c) bv[c] = bias[n0 + wc * 64 + c * 16 + ln];
#pragma unroll
    for (int r = 0; r < 4; ++r)
#pragma unroll
        for (int c = 0; c < 4; ++c)
#pragma unroll
            for (int q = 0; q < 4; ++q) {
                int row = m0 + wr * 64 + r * 16 + lg * 4 + q;
                int col = n0 + wc * 64 + c * 16 + ln;
                Qb[(size_t)row * 512 + col] = f2bf(acc[r][c][q] + bv[c]);
            }
}

// ---------------- attn3: one wave per 16 query rows, all operands direct from L2 --------------
// Grid = 8 batches x 128 q16-tiles = 1024 blocks of 64 threads. Heavy tiles first.
// No __syncthreads, no atomics. P C-layout -> A-layout fixup via 1.28KB private LDS.
__global__ __launch_bounds__(64, 2) void attn3_kernel(const ushort* __restrict__ Xb,
                                                      const ushort* __restrict__ Xt,
                                                      const ushort* __restrict__ Qb,
                                                      float* __restrict__ out) {
    __shared__ ushort Pl[16 * 40];

    int t   = threadIdx.x;
    int bid = blockIdx.x;
    int b   = bid & 7;                 // batch -> XCD affinity
    int qt  = 127 - (bid >> 3);        // heavy tiles (large qt) first

    int ln = t & 15, lg = t >> 4;
    int r0  = qt * 16;
    int gi0 = b * SEQ + r0;

    // Q fragments (A-operand), resident in registers for the whole j-loop
    bf16x8 qf[16];
#pragma unroll
    for (int ks = 0; ks < 16; ++ks)
        qf[ks] = *(const bf16x8*)(Qb + (size_t)(gi0 + ln) * 512 + ks * 32 + lg * 8);

    f32x4 acc[32] = {};
    float den[4] = {0.f, 0.f, 0.f, 0.f};

    const ushort* xbB = Xb + (size_t)b * SEQ * 512;
    const ushort* xtB = Xt + (size_t)b * DIM * SEQ;

    int jsmax = (r0 + 14) >> 5;        // largest needed j is r0+14 (j < i <= r0+15)
    for (int js = 0; js <= jsmax; ++js) {
        int j0 = js * 32;

        // QK^T: S[16 x 32] over K=512, B-frags straight from Xb (L2)
        f32x4 s0v = {}, s1v = {};
        const ushort* xr = xbB + (size_t)j0 * 512;
#pragma unroll
        for (int ks = 0; ks < 16; ++ks) {
            bf16x8 b0 = *(const bf16x8*)(xr + (size_t)ln * 512 + ks * 32 + lg * 8);
            bf16x8 b1 = *(const bf16x8*)(xr + (size_t)(16 + ln) * 512 + ks * 32 + lg * 8);
            s0v = __builtin_amdgcn_mfma_f32_16x16x32_bf16(qf[ks], b0, s0v, 0, 0, 0);
            s1v = __builtin_amdgcn_mfma_f32_16x16x32_bf16(qf[ks], b1, s1v, 0, 0, 0);
        }

        // exp + strict-causal mask + denom partial + P -> private LDS (C-layout -> A-layout)
#pragma unroll
        for (int r = 0; r < 4; ++r) {
            int gi = r0 + lg * 4 + r;
            float p0 = ((j0 + ln) < gi)      ? __expf(s0v[r]) : 0.f;
            float p1 = ((j0 + 16 + ln) < gi) ? __expf(s1v[r]) : 0.f;
            float tr = p0 + p1;
            tr += __shfl_xor(tr, 1);
            tr += __shfl_xor(tr, 2);
            tr += __shfl_xor(tr, 4);
            tr += __shfl_xor(tr, 8);
            den[r] += tr;
            Pl[(lg * 4 + r) * 40 + ln]      = f2bf(p0);
            Pl[(lg * 4 + r) * 40 + 16 + ln] = f2bf(p1);
        }
        bf16x8 pa = *(const bf16x8*)&Pl[ln * 40 + lg * 8];

        // PV: O[16 x 512] += P[16 x 32] @ X_j[32 x 512], B-frags straight from Xt (L2)
        const ushort* xc = xtB + j0;
#pragma unroll
        for (int cf = 0; cf < 32; ++cf) {
            bf16x8 bv = *(const bf16x8*)(xc + (size_t)(cf * 16 + ln) * SEQ + lg * 8);
            acc[cf] = __builtin_amdgcn_mfma_f32_16x16x32_bf16(pa, bv, acc[cf], 0, 0, 0);
        }
    }

    // epilogue: out = acc / (den + 1e-10)
#pragma unroll
    for (int r = 0; r < 4; ++r) {
        float inv = 1.0f / (den[r] + 1e-10f);
#pragma unroll
        for (int cf = 0; cf < 32; ++cf)
            out[(size_t)(gi0 + lg * 4 + r) * 512 + cf * 16 + ln] = acc[cf][r] * inv;
    }
}

extern "C" void kernel_launch(void* const* d_in, const int* in_sizes, int n_in,
                              void* d_out, int out_size, void* d_ws, size_t ws_size,
                              hipStream_t stream) {
    const float* X    = (const float*)d_in[0];
    const float* W    = (const float*)d_in[1];
    const float* bias = (const float*)d_in[2];
    float* out = (float*)d_out;

    // ws layout (ushort elems): Xb[8.4M] | Xt[8.4M] | Qb[8.4M] | Wb[256K]
    ushort* ws = (ushort*)d_ws;
    ushort* Xb = ws;
    ushort* Xt = ws + 8388608;
    ushort* Qb = ws + 16777216;
    ushort* Wb = ws + 25165824;

    prep_kernel<<<dim3(8192), dim3(256), 0, stream>>>(X, Xb, Xt);
    wconv_kernel<<<dim3(128), dim3(256), 0, stream>>>(W, Wb);
    qgemm_kernel<<<dim3(512), dim3(256), 0, stream>>>(Xb, Wb, bias, Qb);
    attn3_kernel<<<dim3(1024), dim3(64), 0, stream>>>(Xb, Xt, Qb, out);
}

// Round 5
// 125.797 us; speedup vs baseline: 3.7578x; 3.7578x over previous
//
#include <hip/hip_runtime.h>
#include <hip/hip_bf16.h>

// B=8, S=2048, H=512. out[b,i,:] = sum_{j<i} exp(q_i.x_j) x_j / (sum_{j<i} exp(q_i.x_j) + 1e-10)
// q = X @ W^T + b.
// R5: de-fused into 3 GEMMs. No online softmax needed (no max-subtract => additive).
//   qgemm : Qb = bf16(X W^T + b)
//   sgemm : P(tile-packed lower-tri, bf16) = exp(mask(Q X^T)), rowsum -> den (atomic)
//   pvgemm: out = (P @ X) * 1/(den+1e-10)
#define BATCH 8
#define SEQ   2048
#define DIM   512

typedef __bf16 bf16x8 __attribute__((ext_vector_type(8)));
typedef float  f32x4  __attribute__((ext_vector_type(4)));

__device__ __forceinline__ ushort f2bf(float f) {
    union { float f; unsigned u; } c; c.f = f;
    unsigned u = c.u;
    u += 0x7fffu + ((u >> 16) & 1u);   // round-to-nearest-even
    return (ushort)(u >> 16);
}

// ---------------- prep: X f32 -> Xb bf16 (row-major) + Xt bf16 (transposed [b][h][s]) ---------
__global__ __launch_bounds__(256) void prep_kernel(const float* __restrict__ X,
                                                   ushort* __restrict__ Xb,
                                                   ushort* __restrict__ Xt) {
    __shared__ ushort T[32 * 33];
    int t   = threadIdx.x;
    int bid = blockIdx.x;              // 8 * 64 * 16 = 8192
    int b   = bid >> 10;
    int st  = (bid >> 4) & 63;
    int ht  = bid & 15;
    int s0 = st * 32, h0 = ht * 32;

    int r  = t >> 3;                   // 0..31 (s within tile)
    int c4 = (t & 7) * 4;              // 0..28 (h within tile)
    size_t src = ((size_t)(b * SEQ + s0 + r)) * DIM + h0 + c4;
    float4 v = *(const float4*)(X + src);
    ushort u0 = f2bf(v.x), u1 = f2bf(v.y), u2 = f2bf(v.z), u3 = f2bf(v.w);
    ushort4 uv; uv.x = u0; uv.y = u1; uv.z = u2; uv.w = u3;
    *(ushort4*)(Xb + src) = uv;
    T[(c4 + 0) * 33 + r] = u0;
    T[(c4 + 1) * 33 + r] = u1;
    T[(c4 + 2) * 33 + r] = u2;
    T[(c4 + 3) * 33 + r] = u3;
    __syncthreads();
    int hh = t >> 3;                   // 0..31 (h)
    int sc = (t & 7) * 4;              // 0..28 (s)
    ushort4 w;
    w.x = T[hh * 33 + sc + 0];
    w.y = T[hh * 33 + sc + 1];
    w.z = T[hh * 33 + sc + 2];
    w.w = T[hh * 33 + sc + 3];
    *(ushort4*)(Xt + ((size_t)(b * DIM + h0 + hh)) * SEQ + s0 + sc) = w;
}

// ---------------- wconv: W f32 -> bf16 ----------------
__global__ __launch_bounds__(256) void wconv_kernel(const float* __restrict__ W,
                                                    ushort* __restrict__ Wb) {
    int gt = blockIdx.x * 256 + threadIdx.x;   // 128 blocks, 8 elems each
    size_t base = (size_t)gt * 8;
    float4 a = *(const float4*)(W + base);
    float4 c = *(const float4*)(W + base + 4);
    ushort4 lo, hi;
    lo.x = f2bf(a.x); lo.y = f2bf(a.y); lo.z = f2bf(a.z); lo.w = f2bf(a.w);
    hi.x = f2bf(c.x); hi.y = f2bf(c.y); hi.z = f2bf(c.z); hi.w = f2bf(c.w);
    *(ushort4*)(Wb + base)     = lo;
    *(ushort4*)(Wb + base + 4) = hi;
}

// ---------------- qgemm: Qb = bf16(Xb @ Wb^T + bias) ----------------
// M=B*S=16384, N=512, K=512. 128x128 tile, 4 waves (each 64x64), K-step 32.
__global__ __launch_bounds__(256, 2) void qgemm_kernel(const ushort* __restrict__ Xb,
                                                       const ushort* __restrict__ Wb,
                                                       const float* __restrict__ bias,
                                                       ushort* __restrict__ Qb) {
    __shared__ ushort At[128 * 40];
    __shared__ ushort Bt[128 * 40];
    int t   = threadIdx.x;
    int bid = blockIdx.x;              // 128 mtiles * 4 ntiles
    int mt = bid >> 2, nt = bid & 3;
    int m0 = mt << 7, n0 = nt << 7;
    int w  = t >> 6, l = t & 63, ln = l & 15, lg = l >> 4;
    int wr = w >> 1, wc = w & 1;

    f32x4 acc[4][4] = {};
    int srow = t >> 2;                 // 0..63
    int sc8  = (t & 3) * 8;            // 0,8,16,24

    for (int ks = 0; ks < 16; ++ks) {
        uint4 va0 = *(const uint4*)(Xb + (size_t)(m0 + srow) * 512 + ks * 32 + sc8);
        uint4 va1 = *(const uint4*)(Xb + (size_t)(m0 + 64 + srow) * 512 + ks * 32 + sc8);
        uint4 vb0 = *(const uint4*)(Wb + (size_t)(n0 + srow) * 512 + ks * 32 + sc8);
        uint4 vb1 = *(const uint4*)(Wb + (size_t)(n0 + 64 + srow) * 512 + ks * 32 + sc8);
        __syncthreads();
        *(uint4*)&At[srow * 40 + sc8]        = va0;
        *(uint4*)&At[(64 + srow) * 40 + sc8] = va1;
        *(uint4*)&Bt[srow * 40 + sc8]        = vb0;
        *(uint4*)&Bt[(64 + srow) * 40 + sc8] = vb1;
        __syncthreads();
        bf16x8 af[4], bfr[4];
#pragma unroll
        for (int r = 0; r < 4; ++r)
            af[r] = *(const bf16x8*)&At[(wr * 64 + r * 16 + ln) * 40 + lg * 8];
#pragma unroll
        for (int c = 0; c < 4; ++c)
            bfr[c] = *(const bf16x8*)&Bt[(wc * 64 + c * 16 + ln) * 40 + lg * 8];
#pragma unroll
        for (int r = 0; r < 4; ++r)
#pragma unroll
            for (int c = 0; c < 4; ++c)
                acc[r][c] = __builtin_amdgcn_mfma_f32_16x16x32_bf16(af[r], bfr[c], acc[r][c], 0, 0, 0);
    }

    float bv[4];
#pragma unroll
    for (int c = 0; c < 4; ++c) bv[c] = bias[n0 + wc * 64 + c * 16 + ln];
#pragma unroll
    for (int r = 0; r < 4; ++r)
#pragma unroll
        for (int c = 0; c < 4; ++c)
#pragma unroll
            for (int q = 0; q < 4; ++q) {
                int row = m0 + wr * 64 + r * 16 + lg * 4 + q;
                int col = n0 + wc * 64 + c * 16 + ln;
                Qb[(size_t)row * 512 + col] = f2bf(acc[r][c][q] + bv[c]);
            }
}

// ---------------- sgemm: P = exp(mask(Q X^T)) into packed lower-tri tiles + rowsum->den -------
// Grid: dim3(G, 136). blockIdx.y = tile index c in [0,136): c -> (it, jt) lower-tri incl diag.
// Pb tile offset = (c*G + bLocal) * 16384, row-major 128x128 bf16.
__global__ __launch_bounds__(256, 2) void sgemm_kernel(const ushort* __restrict__ Qb,
                                                       const ushort* __restrict__ Xb,
                                                       ushort* __restrict__ Pb,
                                                       float* __restrict__ den,
                                                       int g0, int G) {
    __shared__ ushort At[128 * 40];
    __shared__ ushort Bt[128 * 40];
    int t  = threadIdx.x;
    int bL = blockIdx.x;
    int b  = g0 + bL;
    int c  = blockIdx.y;               // 0..135
    int it = 0, base = 0;
    for (;;) { if (c < base + it + 1) break; base += it + 1; ++it; }
    int jt = c - base;

    int m0 = it << 7, n0 = jt << 7;
    int w  = t >> 6, l = t & 63, ln = l & 15, lg = l >> 4;
    int wr = w >> 1, wc = w & 1;

    const ushort* Arow = Qb + (size_t)(b * SEQ + m0) * 512;
    const ushort* Brow = Xb + (size_t)(b * SEQ + n0) * 512;

    f32x4 acc[4][4] = {};
    int srow = t >> 2;
    int sc8  = (t & 3) * 8;

    for (int ks = 0; ks < 16; ++ks) {
        uint4 va0 = *(const uint4*)(Arow + (size_t)srow * 512 + ks * 32 + sc8);
        uint4 va1 = *(const uint4*)(Arow + (size_t)(64 + srow) * 512 + ks * 32 + sc8);
        uint4 vb0 = *(const uint4*)(Brow + (size_t)srow * 512 + ks * 32 + sc8);
        uint4 vb1 = *(const uint4*)(Brow + (size_t)(64 + srow) * 512 + ks * 32 + sc8);
        __syncthreads();
        *(uint4*)&At[srow * 40 + sc8]        = va0;
        *(uint4*)&At[(64 + srow) * 40 + sc8] = va1;
        *(uint4*)&Bt[srow * 40 + sc8]        = vb0;
        *(uint4*)&Bt[(64 + srow) * 40 + sc8] = vb1;
        __syncthreads();
        bf16x8 af[4], bfr[4];
#pragma unroll
        for (int r = 0; r < 4; ++r)
            af[r] = *(const bf16x8*)&At[(wr * 64 + r * 16 + ln) * 40 + lg * 8];
#pragma unroll
        for (int cc = 0; cc < 4; ++cc)
            bfr[cc] = *(const bf16x8*)&Bt[(wc * 64 + cc * 16 + ln) * 40 + lg * 8];
#pragma unroll
        for (int r = 0; r < 4; ++r)
#pragma unroll
            for (int cc = 0; cc < 4; ++cc)
                acc[r][cc] = __builtin_amdgcn_mfma_f32_16x16x32_bf16(af[r], bfr[cc], acc[r][cc], 0, 0, 0);
    }

    ushort* ptile = Pb + ((size_t)c * G + bL) * 16384;
#pragma unroll
    for (int r = 0; r < 4; ++r)
#pragma unroll
        for (int q = 0; q < 4; ++q) {
            int row  = wr * 64 + r * 16 + lg * 4 + q;       // local i
            int grow = m0 + row;                            // in-batch i
            float rs = 0.f;
#pragma unroll
            for (int cc = 0; cc < 4; ++cc) {
                int col = n0 + wc * 64 + cc * 16 + ln;      // in-batch j
                float ex = (col < grow) ? __expf(acc[r][cc][q]) : 0.f;
                rs += ex;
                ptile[row * 128 + (wc * 64 + cc * 16 + ln)] = f2bf(ex);
            }
            rs += __shfl_xor(rs, 1);
            rs += __shfl_xor(rs, 2);
            rs += __shfl_xor(rs, 4);
            rs += __shfl_xor(rs, 8);
            if (ln == 0) unsafeAtomicAdd(&den[b * SEQ + grow], rs);
        }
}

// ---------------- pvgemm: out = (P @ X) * 1/(den+1e-10) --------------------------------------
// Grid: dim3(G, 64). blockIdx.y = t: it = 15-(t>>2) (heavy first), ht = t&3.
// A = Pb packed tiles (it, kt), B = Xt (h-major). K-steps = (it+1)*4 of BK=32.
__global__ __launch_bounds__(256, 2) void pvgemm_kernel(const ushort* __restrict__ Pb,
                                                        const ushort* __restrict__ Xt,
                                                        const float* __restrict__ den,
                                                        float* __restrict__ out,
                                                        int g0, int G) {
    __shared__ ushort At[128 * 40];
    __shared__ ushort Bt[128 * 40];
    int t  = threadIdx.x;
    int bL = blockIdx.x;
    int b  = g0 + bL;
    int tt = blockIdx.y;
    int it = 15 - (tt >> 2);
    int ht = tt & 3;
    int Tit = (it * (it + 1)) >> 1;

    int m0 = it << 7, n0 = ht << 7;
    int w  = t >> 6, l = t & 63, ln = l & 15, lg = l >> 4;
    int wr = w >> 1, wc = w & 1;

    const ushort* BrowX = Xt + (size_t)(b * DIM + n0) * SEQ;

    f32x4 acc[4][4] = {};
    int srow = t >> 2;
    int sc8  = (t & 3) * 8;

    int nks = (it + 1) * 4;
    for (int ks = 0; ks < nks; ++ks) {
        const ushort* ptile = Pb + ((size_t)(Tit + (ks >> 2)) * G + bL) * 16384 + (ks & 3) * 32;
        uint4 va0 = *(const uint4*)(ptile + srow * 128 + sc8);
        uint4 va1 = *(const uint4*)(ptile + (64 + srow) * 128 + sc8);
        uint4 vb0 = *(const uint4*)(BrowX + (size_t)srow * SEQ + ks * 32 + sc8);
        uint4 vb1 = *(const uint4*)(BrowX + (size_t)(64 + srow) * SEQ + ks * 32 + sc8);
        __syncthreads();
        *(uint4*)&At[srow * 40 + sc8]        = va0;
        *(uint4*)&At[(64 + srow) * 40 + sc8] = va1;
        *(uint4*)&Bt[srow * 40 + sc8]        = vb0;
        *(uint4*)&Bt[(64 + srow) * 40 + sc8] = vb1;
        __syncthreads();
        bf16x8 af[4], bfr[4];
#pragma unroll
        for (int r = 0; r < 4; ++r)
            af[r] = *(const bf16x8*)&At[(wr * 64 + r * 16 + ln) * 40 + lg * 8];
#pragma unroll
        for (int cc = 0; cc < 4; ++cc)
            bfr[cc] = *(const bf16x8*)&Bt[(wc * 64 + cc * 16 + ln) * 40 + lg * 8];
#pragma unroll
        for (int r = 0; r < 4; ++r)
#pragma unroll
            for (int cc = 0; cc < 4; ++cc)
                acc[r][cc] = __builtin_amdgcn_mfma_f32_16x16x32_bf16(af[r], bfr[cc], acc[r][cc], 0, 0, 0);
    }

#pragma unroll
    for (int r = 0; r < 4; ++r)
#pragma unroll
        for (int q = 0; q < 4; ++q) {
            int grow = b * SEQ + m0 + wr * 64 + r * 16 + lg * 4 + q;
            float inv = 1.0f / (den[grow] + 1e-10f);
#pragma unroll
            for (int cc = 0; cc < 4; ++cc) {
                int col = n0 + wc * 64 + cc * 16 + ln;
                out[(size_t)grow * 512 + col] = acc[r][cc][q] * inv;
            }
        }
}

extern "C" void kernel_launch(void* const* d_in, const int* in_sizes, int n_in,
                              void* d_out, int out_size, void* d_ws, size_t ws_size,
                              hipStream_t stream) {
    const float* X    = (const float*)d_in[0];
    const float* W    = (const float*)d_in[1];
    const float* bias = (const float*)d_in[2];
    float* out = (float*)d_out;

    // ws layout (bytes): Xb[16.78M] | Xt[16.78M] | Qb[16.78M] | Wb[0.52M] | den[64K] | Pb[G*4.46M]
    ushort* ws = (ushort*)d_ws;
    ushort* Xb = ws;
    ushort* Xt = ws + 8388608;
    ushort* Qb = ws + 16777216;
    ushort* Wb = ws + 25165824;
    float*  den = (float*)((char*)d_ws + 50855936);
    ushort* Pb = (ushort*)((char*)d_ws + 50921472);

    // batch-group size: largest pow2 G<=8 with Pb (G*4,456,448 B) fitting in remaining ws
    size_t avail = (ws_size > 50921472) ? (ws_size - 50921472) : 0;
    int G = 1;
    while (G < 8 && (size_t)(G * 2) * 4456448 <= avail) G *= 2;

    hipMemsetAsync(den, 0, (size_t)BATCH * SEQ * sizeof(float), stream);
    prep_kernel<<<dim3(8192), dim3(256), 0, stream>>>(X, Xb, Xt);
    wconv_kernel<<<dim3(128), dim3(256), 0, stream>>>(W, Wb);
    qgemm_kernel<<<dim3(512), dim3(256), 0, stream>>>(Xb, Wb, bias, Qb);
    for (int g0 = 0; g0 < BATCH; g0 += G) {
        sgemm_kernel<<<dim3(G, 136), dim3(256), 0, stream>>>(Qb, Xb, Pb, den, g0, G);
        pvgemm_kernel<<<dim3(G, 64), dim3(256), 0, stream>>>(Pb, Xt, den, out, g0, G);
    }
}